// Round 5
// baseline (265.436 us; speedup 1.0000x reference)
//
#include <hip/hip_runtime.h>

#define N_NODES 50000
#define N_EDGES 600000
#define D 128
#define NB_SCAN 196       // ceil(50000/256)

typedef __attribute__((ext_vector_type(8))) short short8;
typedef __attribute__((ext_vector_type(4))) float float4v;

static __device__ __forceinline__ float bf2f(unsigned int u16) {
    union { unsigned int i; float f; } v; v.i = u16 << 16; return v.f;
}
static __device__ __forceinline__ unsigned short f2bf(float f) {
    union { float f; unsigned int i; } v; v.f = f;
    unsigned int u = v.i;
    return (unsigned short)((u + 0x7FFFu + ((u >> 16) & 1u)) >> 16);  // RNE
}
static __device__ __forceinline__ float h2f(unsigned int h) {
    unsigned int s = (h >> 15) & 1u, e = (h >> 10) & 0x1fu, m = h & 0x3ffu;
    unsigned int bits = (e == 0) ? (s << 31)
                                 : ((s << 31) | ((e + 112u) << 23) | (m << 13));
    union { unsigned int i; float f; } v; v.i = bits; return v.f;
}

// flags: [0]=ei int32? [1]=et int32? [2]=x fp32? [3]=B fp32? [4]=A fp32?
//        [5]=W0 fp32?  [6]=x fp16 (if not fp32)
__global__ __launch_bounds__(256) void setup(int* __restrict__ flags,
                                             int* __restrict__ cnt,
                                             unsigned int* __restrict__ scanst) {
    int i = blockIdx.x * 256 + threadIdx.x;
    if (i < N_NODES) cnt[i] = 0;
    if (i < 8) flags[i] = 0;
    if (i < 200) scanst[i] = 0;   // status[196] + ticket[196] + done[197]
}

// ALL dtype probes in one launch; block-range partition; per-block LDS vote.
__global__ __launch_bounds__(256) void detect_all(const int* __restrict__ ei,
                                                  const int* __restrict__ et,
                                                  const unsigned int* __restrict__ x,
                                                  const unsigned int* __restrict__ B,
                                                  const unsigned int* __restrict__ A,
                                                  const unsigned int* __restrict__ W0,
                                                  int* __restrict__ flags) {
    __shared__ int sflag;
    if (threadIdx.x == 0) sflag = 0;
    __syncthreads();
    int b = blockIdx.x, acc = 0, fidx;
    if (b < 192) {                // ei: int64 high words all zero <=> flag stays 0
        fidx = 0;
        for (int i = b * 256 + threadIdx.x; i < N_EDGES; i += 192 * 256)
            acc |= ei[2 * i + 1];
    } else if (b < 240) {         // et
        fidx = 1;
        for (int i = (b - 192) * 256 + threadIdx.x; i < N_EDGES / 2; i += 48 * 256)
            acc |= et[2 * i + 1];
    } else if (b < 288) {         // x fp32? (bf16-exponent band escape on low half)
        fidx = 2;
        for (int i = (b - 240) * 256 + threadIdx.x; i < 600000; i += 48 * 256) {
            unsigned int e = (x[i] >> 7) & 0xffu;
            acc |= (e > 0xA0u || e < 0x50u) ? 1 : 0;
        }
    } else if (b < 300) {         // B fp32?
        fidx = 3;
        for (int i = (b - 288) * 256 + threadIdx.x; i < 32768; i += 12 * 256) {
            unsigned int e = (B[i] >> 7) & 0xffu;
            acc |= (e > 0xA0u || e < 0x50u) ? 1 : 0;
        }
    } else if (b == 300) {        // A fp32?
        fidx = 4;
        for (int i = threadIdx.x; i < 10; i += 256) {
            unsigned int e = (A[i] >> 7) & 0xffu;
            acc |= (e > 0xA0u || e < 0x50u) ? 1 : 0;
        }
    } else if (b < 307) {         // W0 fp32?
        fidx = 5;
        for (int i = (b - 301) * 256 + threadIdx.x; i < 8192; i += 6 * 256) {
            unsigned int e = (W0[i] >> 7) & 0xffu;
            acc |= (e > 0xA0u || e < 0x50u) ? 1 : 0;
        }
    } else {                      // x fp16? (b in 307..354)
        fidx = 6;
        for (int i = (b - 307) * 256 + threadIdx.x; i < 300000; i += 48 * 256) {
            unsigned int el = (x[i] >> 7) & 0xffu, eh = (x[i] >> 23) & 0xffu;
            acc |= (el < 0x58u || eh < 0x58u) ? 1 : 0;
        }
    }
    if (acc) sflag = 1;           // benign race
    __syncthreads();
    if (threadIdx.x == 0 && sflag) atomicOr(flags + fidx, 1);
}

static __device__ __forceinline__ float loadw(const void* p, int idx, int f32) {
    return f32 ? ((const float*)p)[idx] : bf2f(((const unsigned short*)p)[idx]);
}

// Fused: ei+et normalization + target histogram + Wall build.
// Wall layout: wcatW[f][d] bf16, f = slot*128 + o, slot 0 = W0, slot 1+r = W_r.
// blocks 0..4687: ei; 4688..7031: et; 7032..7415: wcatW (98304 elems).
__global__ __launch_bounds__(256) void norm_hist_w(const int* __restrict__ ei,
                                                   const int* __restrict__ et,
                                                   int* __restrict__ idx32,
                                                   int* __restrict__ et32,
                                                   int* __restrict__ cnt,
                                                   const void* __restrict__ A,
                                                   const void* __restrict__ B,
                                                   const void* __restrict__ W0,
                                                   unsigned short* __restrict__ wcatW,
                                                   const int* __restrict__ flags) {
    int b = blockIdx.x;
    if (b < 4688) {
        int i = b * 256 + threadIdx.x;
        if (i < 2 * N_EDGES) {
            int v = flags[0] ? ei[i] : ei[2 * i];
            idx32[i] = v;
            if (i >= N_EDGES && (unsigned)v < (unsigned)N_NODES)
                atomicAdd(&cnt[v], 1);   // count by target
        }
    } else if (b < 7032) {
        int i = (b - 4688) * 256 + threadIdx.x;
        if (i < N_EDGES) et32[i] = flags[1] ? et[i] : et[2 * i];
    } else {
        int idx = (b - 7032) * 256 + threadIdx.x;  // 98304 exact
        int fB = flags[3], fA = flags[4], fW = flags[5];
        int f = idx >> 7, d = idx & 127;
        int slot = f >> 7, o = f & 127;
        float v;
        if (slot == 0) {
            v = loadw(W0, o * D + d, fW);
        } else {
            int r = slot - 1;
            v = 0.f;
#pragma unroll
            for (int j = 0; j < 4; ++j)
                v += loadw(A, r * 4 + j, fA) * loadw(B, (j * D + o) * D + d, fB);
        }
        wcatW[idx] = f2bf(v);
    }
}

// Tier-3 weights: wcatT6F[slot][d][o] fp32 = W_slot[o][d]
__global__ __launch_bounds__(256) void prep_wt6_direct(const void* __restrict__ A,
                                                       const void* __restrict__ B,
                                                       const void* __restrict__ W0,
                                                       float* __restrict__ wcatT6F,
                                                       const int* __restrict__ flags) {
    int idx = blockIdx.x * 256 + threadIdx.x;  // 98304 exact
    int fB = flags[3], fA = flags[4], fW = flags[5];
    int slot = idx >> 14, d = (idx >> 7) & 127, o = idx & 127;
    float v;
    if (slot == 0) {
        v = loadw(W0, o * D + d, fW);
    } else {
        int r = slot - 1;
        v = 0.f;
#pragma unroll
        for (int j = 0; j < 4; ++j)
            v += loadw(A, r * 4 + j, fA) * loadw(B, (j * D + o) * D + d, fB);
    }
    wcatT6F[idx] = v;
}

// Y[50000][768] bf16 = x @ Wall^T.  v3: ZERO LDS, ZERO barriers.
//  - x B-fragments are nt-invariant -> loaded once into 8 short8 regs/lane
//    (dtype conversion in-register)
//  - W A-fragments read per-nt directly from L2 (wcatW is 196KB, L2-resident);
//    16 independent 16B loads per nt hide under 32 MFMAs + TLP
//  - 128-thread blocks, 1563 blocks (~6/CU): latency hidden by occupancy
//  - fragment<->output mapping identical to verified R3 kernel
__global__ __launch_bounds__(128) void gemm_y(const void* __restrict__ xraw,
                                              const unsigned short* __restrict__ wcatW,
                                              unsigned short* __restrict__ Ybf,
                                              const int* __restrict__ flags) {
    int tid = threadIdx.x;
    int m0 = blockIdx.x * 32;                   // 1563 blocks
    int wid = tid >> 6, lane = tid & 63;
    int wf = wid * 64;                          // wave's f-half within each 128-f tile
    int lm = lane & 15, kg = lane >> 4;
    int f32 = flags[2], f16 = flags[6];
    const short8 z8 = {0, 0, 0, 0, 0, 0, 0, 0};

    // ---- x fragments (B-operand) into registers; shared across all 6 nt
    short8 xb[2][4];
#pragma unroll
    for (int j = 0; j < 2; ++j) {
        int node = m0 + j * 16 + lm;
        if (node >= N_NODES) {
#pragma unroll
            for (int kb = 0; kb < 4; ++kb) xb[j][kb] = z8;
        } else if (f32) {
            const float4* xp = (const float4*)xraw + (((size_t)node * D) >> 2);
#pragma unroll
            for (int kb = 0; kb < 4; ++kb) {
                float4 u0 = xp[kb * 8 + kg * 2];
                float4 u1 = xp[kb * 8 + kg * 2 + 1];
                union { short8 s; unsigned short h[8]; } pk;
                pk.h[0] = f2bf(u0.x); pk.h[1] = f2bf(u0.y);
                pk.h[2] = f2bf(u0.z); pk.h[3] = f2bf(u0.w);
                pk.h[4] = f2bf(u1.x); pk.h[5] = f2bf(u1.y);
                pk.h[6] = f2bf(u1.z); pk.h[7] = f2bf(u1.w);
                xb[j][kb] = pk.s;
            }
        } else if (f16) {
            const uint4* xp4 = (const uint4*)xraw + (((size_t)node * D) >> 3);
#pragma unroll
            for (int kb = 0; kb < 4; ++kb) {
                uint4 u = xp4[kb * 4 + kg];
                unsigned int ww[4] = {u.x, u.y, u.z, u.w};
                union { short8 s; unsigned short h[8]; } pk;
#pragma unroll
                for (int z = 0; z < 4; ++z) {
                    pk.h[2 * z]     = f2bf(h2f(ww[z] & 0xffffu));
                    pk.h[2 * z + 1] = f2bf(h2f(ww[z] >> 16));
                }
                xb[j][kb] = pk.s;
            }
        } else {  // bf16 passthrough
            const uint4* xp4 = (const uint4*)xraw + (((size_t)node * D) >> 3);
#pragma unroll
            for (int kb = 0; kb < 4; ++kb) {
                union { uint4 v; short8 s; } cv; cv.v = xp4[kb * 4 + kg];
                xb[j][kb] = cv.s;
            }
        }
    }

    for (int nt = 0; nt < 6; ++nt) {
        // lane's W base: row (nt*128 + wf + lm), col kg*8
        const unsigned short* wp = wcatW + (size_t)(nt * 128 + wf + lm) * D + kg * 8;
        float4v acc[4][2];
#pragma unroll
        for (int i = 0; i < 4; ++i)
#pragma unroll
            for (int j = 0; j < 2; ++j) acc[i][j] = (float4v){0.f, 0.f, 0.f, 0.f};

#pragma unroll
        for (int kb = 0; kb < 4; ++kb) {
            short8 a0 = *(const short8*)(wp + kb * 32 + 0 * 16 * D);
            short8 a1 = *(const short8*)(wp + kb * 32 + 1 * 16 * D);
            short8 a2 = *(const short8*)(wp + kb * 32 + 2 * 16 * D);
            short8 a3 = *(const short8*)(wp + kb * 32 + 3 * 16 * D);
            acc[0][0] = __builtin_amdgcn_mfma_f32_16x16x32_bf16(a0, xb[0][kb], acc[0][0], 0, 0, 0);
            acc[0][1] = __builtin_amdgcn_mfma_f32_16x16x32_bf16(a0, xb[1][kb], acc[0][1], 0, 0, 0);
            acc[1][0] = __builtin_amdgcn_mfma_f32_16x16x32_bf16(a1, xb[0][kb], acc[1][0], 0, 0, 0);
            acc[1][1] = __builtin_amdgcn_mfma_f32_16x16x32_bf16(a1, xb[1][kb], acc[1][1], 0, 0, 0);
            acc[2][0] = __builtin_amdgcn_mfma_f32_16x16x32_bf16(a2, xb[0][kb], acc[2][0], 0, 0, 0);
            acc[2][1] = __builtin_amdgcn_mfma_f32_16x16x32_bf16(a2, xb[1][kb], acc[2][1], 0, 0, 0);
            acc[3][0] = __builtin_amdgcn_mfma_f32_16x16x32_bf16(a3, xb[0][kb], acc[3][0], 0, 0, 0);
            acc[3][1] = __builtin_amdgcn_mfma_f32_16x16x32_bf16(a3, xb[1][kb], acc[3][1], 0, 0, 0);
        }

        // epilogue: col(lm) = node, (kg,reg) = f -> lane packs 4 consecutive f
#pragma unroll
        for (int i = 0; i < 4; ++i) {
            int f0 = nt * 128 + wf + i * 16 + kg * 4;
#pragma unroll
            for (int j = 0; j < 2; ++j) {
                int node = m0 + j * 16 + lm;
                if (node < N_NODES) {
                    union { unsigned long long u; unsigned short h[4]; } pk;
                    pk.h[0] = f2bf(acc[i][j][0]); pk.h[1] = f2bf(acc[i][j][1]);
                    pk.h[2] = f2bf(acc[i][j][2]); pk.h[3] = f2bf(acc[i][j][3]);
                    *(unsigned long long*)(Ybf + (size_t)node * 768 + f0) = pk.u;
                }
            }
        }
    }
}

// Fused scan (ticketed decoupled lookback) + place.  196 blocks <= 256 CUs
// => all co-resident, so the done-counter grid barrier cannot deadlock.
#define SC_AGG (1u << 30)
#define SC_PRE (1u << 31)
__global__ __launch_bounds__(256) void scan_place(const int* __restrict__ cnt,
                                                  int* __restrict__ offsets,
                                                  int* __restrict__ cursor,
                                                  unsigned int* __restrict__ scanst,
                                                  const int* __restrict__ src,
                                                  const int* __restrict__ tgt,
                                                  const int* __restrict__ et,
                                                  int* __restrict__ entries) {
    __shared__ int sh[256];
    __shared__ int sbid, sprefix;
    unsigned int* status = scanst;          // [196]
    unsigned int* ticket = scanst + 196;
    unsigned int* done   = scanst + 197;
    int t = threadIdx.x;
    if (t == 0) sbid = (int)atomicAdd(ticket, 1u);
    __syncthreads();
    int bid = sbid;
    int idx = bid * 256 + t;
    int v = (idx < N_NODES) ? cnt[idx] : 0;
    sh[t] = v;
    __syncthreads();
    for (int off = 1; off < 256; off <<= 1) {
        int a = (t >= off) ? sh[t - off] : 0;
        __syncthreads();
        sh[t] += a;
        __syncthreads();
    }
    if (t == 0) {
        int total = sh[255];
        atomicExch(&status[bid], (unsigned int)total | SC_AGG);
        int prefix = 0;
        for (int j = bid - 1; j >= 0; --j) {
            unsigned int s;
            do { s = atomicAdd(&status[j], 0u); } while ((s & (SC_AGG | SC_PRE)) == 0u);
            prefix += (int)(s & 0x3FFFFFFFu);
            if (s & SC_PRE) break;
        }
        atomicExch(&status[bid], (unsigned int)(prefix + total) | SC_PRE);
        sprefix = prefix;
    }
    __syncthreads();
    int excl = sh[t] - v + sprefix;
    if (idx < N_NODES) {
        offsets[idx] = excl;
        atomicExch(&cursor[idx], excl);     // device-scope publish for place phase
        if (idx == N_NODES - 1) offsets[N_NODES] = excl + v;
    }
    __syncthreads();                        // all this block's cursor atomics done
    if (t == 0) {
        atomicAdd(done, 1u);
        while (atomicAdd(done, 0u) < (unsigned)NB_SCAN) __builtin_amdgcn_s_sleep(1);
    }
    __syncthreads();
    // ---- place phase: block bid owns edges [bid*3062, bid*3062+3062)
    int e0 = bid * 3062;
    int e1 = e0 + 3062; if (e1 > N_EDGES) e1 = N_EDGES;
    for (int e = e0 + t; e < e1; e += 256) {
        int s = src[e], g = tgt[e], r = et[e];
        if ((unsigned)s >= (unsigned)N_NODES || (unsigned)g >= (unsigned)N_NODES || (unsigned)r >= 5u) continue;
        int pos = atomicAdd(&cursor[g], 1);
        entries[pos] = s * 8 + r;
    }
}

// agg_out: per node (1 wave): out[n] = Y[n][0:128] + sum_edges Y[src][(1+r)*128..].
// Relation baked into the SCALAR gather address -> branch-free inner loop.
__global__ __launch_bounds__(256) void agg_out(const int* __restrict__ offsets,
                                               const int* __restrict__ entries,
                                               const unsigned int* __restrict__ Y32,
                                               float* __restrict__ outF) {
    int tid = threadIdx.x;
    int wid = tid >> 6, lane = tid & 63;
    int n = __builtin_amdgcn_readfirstlane(blockIdx.x * 4 + wid);  // 12500 blocks
    int beg = __builtin_amdgcn_readfirstlane(offsets[n]);
    int end = __builtin_amdgcn_readfirstlane(offsets[n + 1]);
    unsigned int selfw = Y32[(size_t)n * 384 + lane];              // cols 0..127 (W0 x_n)
    float a0 = bf2f(selfw & 0xffffu), a1 = bf2f(selfw >> 16);

    for (int base = beg; base < end; base += 64) {
        int cnt = end - base;
        if (cnt > 64) cnt = 64;
        // over-read past segment end is safe: entries is followed by idx32 in ws
        int eload = entries[base + lane];
        int j = 0;
        for (; j + 3 < cnt; j += 4) {       // 4 independent gathers in flight
            int en0 = __builtin_amdgcn_readlane(eload, j);
            int en1 = __builtin_amdgcn_readlane(eload, j + 1);
            int en2 = __builtin_amdgcn_readlane(eload, j + 2);
            int en3 = __builtin_amdgcn_readlane(eload, j + 3);
            unsigned int r0 = (unsigned)(en0 >> 3) < (unsigned)N_NODES ? (unsigned)(en0 >> 3) : 0u;
            unsigned int r1 = (unsigned)(en1 >> 3) < (unsigned)N_NODES ? (unsigned)(en1 >> 3) : 0u;
            unsigned int r2 = (unsigned)(en2 >> 3) < (unsigned)N_NODES ? (unsigned)(en2 >> 3) : 0u;
            unsigned int r3 = (unsigned)(en3 >> 3) < (unsigned)N_NODES ? (unsigned)(en3 >> 3) : 0u;
            unsigned int x0 = Y32[(size_t)r0 * 384 + ((en0 & 7) + 1) * 64 + lane];
            unsigned int x1 = Y32[(size_t)r1 * 384 + ((en1 & 7) + 1) * 64 + lane];
            unsigned int x2 = Y32[(size_t)r2 * 384 + ((en2 & 7) + 1) * 64 + lane];
            unsigned int x3 = Y32[(size_t)r3 * 384 + ((en3 & 7) + 1) * 64 + lane];
            a0 += bf2f(x0 & 0xffffu); a1 += bf2f(x0 >> 16);
            a0 += bf2f(x1 & 0xffffu); a1 += bf2f(x1 >> 16);
            a0 += bf2f(x2 & 0xffffu); a1 += bf2f(x2 >> 16);
            a0 += bf2f(x3 & 0xffffu); a1 += bf2f(x3 >> 16);
        }
        for (; j < cnt; ++j) {
            int en = __builtin_amdgcn_readlane(eload, j);
            unsigned int rr = (unsigned)(en >> 3) < (unsigned)N_NODES ? (unsigned)(en >> 3) : 0u;
            unsigned int xw = Y32[(size_t)rr * 384 + ((en & 7) + 1) * 64 + lane];
            a0 += bf2f(xw & 0xffffu); a1 += bf2f(xw >> 16);
        }
    }

    *((float2*)outF + (size_t)n * 64 + lane) = make_float2(a0, a1);
}

// ---- Tier-3 fallback (tiny ws) ----
static __device__ __forceinline__ float2 readx2(const void* x, int node, int lane,
                                                int f32, int f16) {
    if (f32) return *((const float2*)x + (size_t)node * 64 + lane);
    unsigned int w = *((const unsigned int*)x + (size_t)node * 64 + lane);
    float2 r;
    if (f16) { r.x = h2f(w & 0xffffu); r.y = h2f(w >> 16); }
    else     { r.x = bf2f(w & 0xffffu); r.y = bf2f(w >> 16); }
    return r;
}

__global__ __launch_bounds__(256) void self_raw(const void* __restrict__ x,
                                                const float* __restrict__ wcatT6F,
                                                float* __restrict__ outF,
                                                const int* __restrict__ flags) {
    int t = blockIdx.x * 256 + threadIdx.x;
    int n = t >> 6, lane = t & 63;
    int f32 = flags[2], f16 = flags[6];
    float2 xp = readx2(x, n, lane, f32, f16);
    float m0 = 0.f, m1 = 0.f;
#pragma unroll 8
    for (int dp = 0; dp < 64; ++dp) {
        float xa = __shfl(xp.x, dp);
        float xc = __shfl(xp.y, dp);
        float2 w0 = *(const float2*)(wcatT6F + (size_t)(2 * dp) * D + 2 * lane);
        float2 w1 = *(const float2*)(wcatT6F + (size_t)(2 * dp + 1) * D + 2 * lane);
        m0 += xa * w0.x + xc * w1.x;
        m1 += xa * w0.y + xc * w1.y;
    }
    *((float2*)outF + (size_t)n * 64 + lane) = make_float2(m0, m1);
}

__global__ __launch_bounds__(256) void edge_raw(const int* __restrict__ src,
                                                const int* __restrict__ tgt,
                                                const int* __restrict__ et,
                                                const void* __restrict__ x,
                                                const float* __restrict__ wcatT6F,
                                                float* __restrict__ outF,
                                                const int* __restrict__ flags) {
    int t = blockIdx.x * 256 + threadIdx.x;
    int e = t >> 6, lane = t & 63;
    if (e >= N_EDGES) return;
    int f32 = flags[2], f16 = flags[6];
    int s = src[e], g = tgt[e], r = et[e];
    if ((unsigned)s >= (unsigned)N_NODES || (unsigned)g >= (unsigned)N_NODES || (unsigned)r >= 5u) return;
    float2 xp = readx2(x, s, lane, f32, f16);
    const float* wt = wcatT6F + (size_t)(1 + r) * D * D;
    float m0 = 0.f, m1 = 0.f;
#pragma unroll 8
    for (int dp = 0; dp < 64; ++dp) {
        float xa = __shfl(xp.x, dp);
        float xc = __shfl(xp.y, dp);
        float2 w0 = *(const float2*)(wt + (size_t)(2 * dp) * D + 2 * lane);
        float2 w1 = *(const float2*)(wt + (size_t)(2 * dp + 1) * D + 2 * lane);
        m0 += xa * w0.x + xc * w1.x;
        m1 += xa * w0.y + xc * w1.y;
    }
    float* ap = outF + (size_t)g * D + lane * 2;
    atomicAdd(ap + 0, m0);
    atomicAdd(ap + 1, m1);
}

extern "C" void kernel_launch(void* const* d_in, const int* in_sizes, int n_in,
                              void* d_out, int out_size, void* d_ws, size_t ws_size,
                              hipStream_t stream) {
    // identify inputs by element count (order-proof; all counts distinct)
    const void* x  = nullptr; const int* ei = nullptr; const int* et = nullptr;
    const void* B  = nullptr; const void* A = nullptr; const void* W0 = nullptr;
    for (int i = 0; i < n_in; ++i) {
        switch (in_sizes[i]) {
            case 6400000: x  = d_in[i]; break;
            case 1200000: ei = (const int*)d_in[i]; break;
            case 600000:  et = (const int*)d_in[i]; break;
            case 65536:   B  = d_in[i]; break;
            case 20:      A  = d_in[i]; break;
            case 16384:   W0 = d_in[i]; break;
            default: break;
        }
    }
    if (!x || !ei || !et || !B || !A || !W0) {
        x  = d_in[0]; ei = (const int*)d_in[1]; et = (const int*)d_in[2];
        B  = d_in[3]; A  = d_in[4]; W0 = d_in[5];
    }
    float* outF = (float*)d_out;  // [50000,128] fp32

    char* ws = (char*)d_ws;
    int*   flags   = (int*)(ws + 0);                           // 256 B
    float* wcatT6F = (float*)(ws + 256);                       // 393,216
    unsigned short* wcatW = (unsigned short*)(ws + 393472);    // 196,608 (Wall bf16 [768][128])
    int* offsets  = (int*)(ws + 590080);                       // 200,004
    int* cursor   = (int*)(ws + 790144);                       // 200,000
    int* cnt      = (int*)(ws + 990144);                       // 200,000
    unsigned int* scanst = (unsigned int*)(ws + 1190144);      // 1,024 (status+ticket+done)
    int* entries  = (int*)(ws + 1191168);                      // 2,400,000
    int* idx32    = (int*)(ws + 3591168);                      // 4,800,000
    int* et32     = (int*)(ws + 8391168);                      // 2,400,000
    unsigned short* Y = (unsigned short*)(ws + 10791168);      // 76,800,000  (Y [50000][768] bf16)
    const size_t needMain = 10791168ull + 76800000ull;         // 87,591,168
    const size_t needT3   = 393472ull;

    int* src32 = idx32;
    int* tgt32 = idx32 + N_EDGES;

    setup<<<NB_SCAN, 256, 0, stream>>>(flags, cnt, scanst);
    detect_all<<<355, 256, 0, stream>>>(ei, et, (const unsigned int*)x,
                                        (const unsigned int*)B, (const unsigned int*)A,
                                        (const unsigned int*)W0, flags);

    if (ws_size >= needMain) {
        norm_hist_w<<<7416, 256, 0, stream>>>(ei, et, idx32, et32, cnt,
                                              A, B, W0, wcatW, flags);
        gemm_y<<<1563, 128, 0, stream>>>(x, wcatW, Y, flags);
        scan_place<<<NB_SCAN, 256, 0, stream>>>(cnt, offsets, cursor, scanst,
                                                src32, tgt32, et32, entries);
        agg_out<<<12500, 256, 0, stream>>>(offsets, entries, (const unsigned int*)Y, outF);
    } else if (ws_size >= needT3) {
        prep_wt6_direct<<<384, 256, 0, stream>>>(A, B, W0, wcatT6F, flags);
        self_raw<<<12500, 256, 0, stream>>>(x, wcatT6F, outF, flags);
        edge_raw<<<150000, 256, 0, stream>>>(ei, ei + N_EDGES, et, x, wcatT6F, outF, flags);
    }
}

// Round 6
// 229.133 us; speedup vs baseline: 1.1584x; 1.1584x over previous
//
#include <hip/hip_runtime.h>

#define N_NODES 50000
#define N_EDGES 600000
#define D 128
#define KTOT 768          // 128 self + 5*128 relation-aggregated
#define NB_SCAN 196       // ceil(50000/256)

typedef __attribute__((ext_vector_type(8))) short short8;
typedef __attribute__((ext_vector_type(4))) float float4v;

static __device__ __forceinline__ float bf2f(unsigned int u16) {
    union { unsigned int i; float f; } v; v.i = u16 << 16; return v.f;
}
static __device__ __forceinline__ unsigned short f2bf(float f) {
    union { float f; unsigned int i; } v; v.f = f;
    unsigned int u = v.i;
    return (unsigned short)((u + 0x7FFFu + ((u >> 16) & 1u)) >> 16);  // RNE
}
static __device__ __forceinline__ float h2f(unsigned int h) {
    unsigned int s = (h >> 15) & 1u, e = (h >> 10) & 0x1fu, m = h & 0x3ffu;
    unsigned int bits = (e == 0) ? (s << 31)
                                 : ((s << 31) | ((e + 112u) << 23) | (m << 13));
    union { unsigned int i; float f; } v; v.i = bits; return v.f;
}

// flags: [0]=ei int32? [1]=et int32? [2]=x fp32? [3]=B fp32? [4]=A fp32?
//        [5]=W0 fp32?  [6]=x fp16 (if not fp32)
__global__ __launch_bounds__(256) void setup(int* __restrict__ flags,
                                             int* __restrict__ cnt,
                                             unsigned int* __restrict__ scanst) {
    int i = blockIdx.x * 256 + threadIdx.x;
    if (i < N_NODES) cnt[i] = 0;
    if (i < 8) flags[i] = 0;
    if (i < 200) scanst[i] = 0;   // status[196] + ticket + done
}

// ALL dtype probes in one launch; block-range partition; per-block LDS vote.
__global__ __launch_bounds__(256) void detect_all(const int* __restrict__ ei,
                                                  const int* __restrict__ et,
                                                  const unsigned int* __restrict__ x,
                                                  const unsigned int* __restrict__ B,
                                                  const unsigned int* __restrict__ A,
                                                  const unsigned int* __restrict__ W0,
                                                  int* __restrict__ flags) {
    __shared__ int sflag;
    if (threadIdx.x == 0) sflag = 0;
    __syncthreads();
    int b = blockIdx.x, acc = 0, fidx;
    if (b < 192) {                // ei: int64 high words all zero <=> flag stays 0
        fidx = 0;
        for (int i = b * 256 + threadIdx.x; i < N_EDGES; i += 192 * 256)
            acc |= ei[2 * i + 1];
    } else if (b < 240) {         // et
        fidx = 1;
        for (int i = (b - 192) * 256 + threadIdx.x; i < N_EDGES / 2; i += 48 * 256)
            acc |= et[2 * i + 1];
    } else if (b < 288) {         // x fp32? (bf16-exponent band escape on low half)
        fidx = 2;
        for (int i = (b - 240) * 256 + threadIdx.x; i < 600000; i += 48 * 256) {
            unsigned int e = (x[i] >> 7) & 0xffu;
            acc |= (e > 0xA0u || e < 0x50u) ? 1 : 0;
        }
    } else if (b < 300) {         // B fp32?
        fidx = 3;
        for (int i = (b - 288) * 256 + threadIdx.x; i < 32768; i += 12 * 256) {
            unsigned int e = (B[i] >> 7) & 0xffu;
            acc |= (e > 0xA0u || e < 0x50u) ? 1 : 0;
        }
    } else if (b == 300) {        // A fp32?
        fidx = 4;
        for (int i = threadIdx.x; i < 10; i += 256) {
            unsigned int e = (A[i] >> 7) & 0xffu;
            acc |= (e > 0xA0u || e < 0x50u) ? 1 : 0;
        }
    } else if (b < 307) {         // W0 fp32?
        fidx = 5;
        for (int i = (b - 301) * 256 + threadIdx.x; i < 8192; i += 6 * 256) {
            unsigned int e = (W0[i] >> 7) & 0xffu;
            acc |= (e > 0xA0u || e < 0x50u) ? 1 : 0;
        }
    } else {                      // x fp16? (b in 307..354)
        fidx = 6;
        for (int i = (b - 307) * 256 + threadIdx.x; i < 300000; i += 48 * 256) {
            unsigned int el = (x[i] >> 7) & 0xffu, eh = (x[i] >> 23) & 0xffu;
            acc |= (el < 0x58u || eh < 0x58u) ? 1 : 0;
        }
    }
    if (acc) sflag = 1;           // benign race
    __syncthreads();
    if (threadIdx.x == 0 && sflag) atomicOr(flags + fidx, 1);
}

static __device__ __forceinline__ float loadw(const void* p, int idx, int f32) {
    return f32 ? ((const float*)p)[idx] : bf2f(((const unsigned short*)p)[idx]);
}

// Fused: ei+et normalization + target histogram + weight build + x->bf16 conv.
// idx32/et32 are DE-ALIASED from Xcat, so conv can run in the same launch.
// blocks 0..4687: ei; 4688..7031: et; 7032..7415: wcatB; 7416..13665: conv_x.
__global__ __launch_bounds__(256) void norm_hist_conv(const int* __restrict__ ei,
                                                      const int* __restrict__ et,
                                                      int* __restrict__ idx32,
                                                      int* __restrict__ et32,
                                                      int* __restrict__ cnt,
                                                      const void* __restrict__ A,
                                                      const void* __restrict__ B,
                                                      const void* __restrict__ W0,
                                                      unsigned short* __restrict__ wcatB,
                                                      const void* __restrict__ xraw,
                                                      unsigned short* __restrict__ Xcat,
                                                      const int* __restrict__ flags) {
    int b = blockIdx.x;
    if (b < 4688) {
        int i = b * 256 + threadIdx.x;
        if (i < 2 * N_EDGES) {
            int v = flags[0] ? ei[i] : ei[2 * i];
            idx32[i] = v;
            if (i >= N_EDGES && (unsigned)v < (unsigned)N_NODES)
                atomicAdd(&cnt[v], 1);   // count by target
        }
    } else if (b < 7032) {
        int i = (b - 4688) * 256 + threadIdx.x;
        if (i < N_EDGES) et32[i] = flags[1] ? et[i] : et[2 * i];
    } else if (b < 7416) {
        int idx = (b - 7032) * 256 + threadIdx.x;  // 98304 exact
        int fB = flags[3], fA = flags[4], fW = flags[5];
        int o = idx / KTOT, k = idx % KTOT;
        float v;
        if (k < D) {
            v = loadw(W0, o * D + k, fW);
        } else {
            int r = (k - D) >> 7, d = (k - D) & 127;
            v = 0.f;
#pragma unroll
            for (int j = 0; j < 4; ++j)
                v += loadw(A, r * 4 + j, fA) * loadw(B, (j * D + o) * D + d, fB);
        }
        wcatB[idx] = f2bf(v);
    } else {
        int idx = (b - 7416) * 256 + threadIdx.x;  // 1,600,000 exact (6250 blocks)
        int n = idx >> 5, cg = idx & 31;
        int f32 = flags[2], f16 = flags[6];
        unsigned short o0, o1, o2, o3;
        if (f32) {
            float4 v = *((const float4*)xraw + idx);
            o0 = f2bf(v.x); o1 = f2bf(v.y); o2 = f2bf(v.z); o3 = f2bf(v.w);
        } else {
            uint2 v = *((const uint2*)xraw + idx);
            if (f16) {
                o0 = f2bf(h2f(v.x & 0xffffu)); o1 = f2bf(h2f(v.x >> 16));
                o2 = f2bf(h2f(v.y & 0xffffu)); o3 = f2bf(h2f(v.y >> 16));
            } else {
                o0 = v.x & 0xffffu; o1 = v.x >> 16; o2 = v.y & 0xffffu; o3 = v.y >> 16;
            }
        }
        unsigned long long pack = (unsigned long long)o0 | ((unsigned long long)o1 << 16) |
                                  ((unsigned long long)o2 << 32) | ((unsigned long long)o3 << 48);
        *(unsigned long long*)(Xcat + (size_t)n * KTOT + cg * 4) = pack;
    }
}

// Tier-3 weights: wcatT6F[slot][d][o] fp32 = W_slot[o][d]
__global__ __launch_bounds__(256) void prep_wt6_direct(const void* __restrict__ A,
                                                       const void* __restrict__ B,
                                                       const void* __restrict__ W0,
                                                       float* __restrict__ wcatT6F,
                                                       const int* __restrict__ flags) {
    int idx = blockIdx.x * 256 + threadIdx.x;  // 98304 exact
    int fB = flags[3], fA = flags[4], fW = flags[5];
    int slot = idx >> 14, d = (idx >> 7) & 127, o = idx & 127;
    float v;
    if (slot == 0) {
        v = loadw(W0, o * D + d, fW);
    } else {
        int r = slot - 1;
        v = 0.f;
#pragma unroll
        for (int j = 0; j < 4; ++j)
            v += loadw(A, r * 4 + j, fA) * loadw(B, (j * D + o) * D + d, fB);
    }
    wcatT6F[idx] = v;
}

// Fused scan (ticketed decoupled lookback) + place.  196 blocks <= 256 CUs
// => all co-resident, so the done-counter grid barrier cannot deadlock.
// Validated on hardware in R3/R4/R5 benches.
#define SC_AGG (1u << 30)
#define SC_PRE (1u << 31)
__global__ __launch_bounds__(256) void scan_place(const int* __restrict__ cnt,
                                                  int* __restrict__ offsets,
                                                  int* __restrict__ cursor,
                                                  unsigned int* __restrict__ scanst,
                                                  const int* __restrict__ src,
                                                  const int* __restrict__ tgt,
                                                  const int* __restrict__ et,
                                                  int* __restrict__ entries) {
    __shared__ int sh[256];
    __shared__ int sbid, sprefix;
    unsigned int* status = scanst;          // [196]
    unsigned int* ticket = scanst + 196;
    unsigned int* done   = scanst + 197;
    int t = threadIdx.x;
    if (t == 0) sbid = (int)atomicAdd(ticket, 1u);
    __syncthreads();
    int bid = sbid;
    int idx = bid * 256 + t;
    int v = (idx < N_NODES) ? cnt[idx] : 0;
    sh[t] = v;
    __syncthreads();
    for (int off = 1; off < 256; off <<= 1) {
        int a = (t >= off) ? sh[t - off] : 0;
        __syncthreads();
        sh[t] += a;
        __syncthreads();
    }
    if (t == 0) {
        int total = sh[255];
        atomicExch(&status[bid], (unsigned int)total | SC_AGG);
        int prefix = 0;
        for (int j = bid - 1; j >= 0; --j) {
            unsigned int s;
            do { s = atomicAdd(&status[j], 0u); } while ((s & (SC_AGG | SC_PRE)) == 0u);
            prefix += (int)(s & 0x3FFFFFFFu);
            if (s & SC_PRE) break;
        }
        atomicExch(&status[bid], (unsigned int)(prefix + total) | SC_PRE);
        sprefix = prefix;
    }
    __syncthreads();
    int excl = sh[t] - v + sprefix;
    if (idx < N_NODES) {
        offsets[idx] = excl;
        atomicExch(&cursor[idx], excl);     // device-scope publish for place phase
        if (idx == N_NODES - 1) offsets[N_NODES] = excl + v;
    }
    __syncthreads();                        // all this block's cursor atomics done
    if (t == 0) {
        atomicAdd(done, 1u);
        while (atomicAdd(done, 0u) < (unsigned)NB_SCAN) __builtin_amdgcn_s_sleep(1);
    }
    __syncthreads();
    // ---- place phase: block bid owns edges [bid*3062, bid*3062+3062)
    int e0 = bid * 3062;
    int e1 = e0 + 3062; if (e1 > N_EDGES) e1 = N_EDGES;
    for (int e = e0 + t; e < e1; e += 256) {
        int s = src[e], g = tgt[e], r = et[e];
        if ((unsigned)s >= (unsigned)N_NODES || (unsigned)g >= (unsigned)N_NODES || (unsigned)r >= 5u) continue;
        int pos = atomicAdd(&cursor[g], 1);
        entries[pos] = s * 8 + r;
    }
}

// aggregate v5 (benched in R1/R2 at <41us): ONE wave per node; entries fetched
// once coalesced, each entry extracted via v_readlane -> SGPR (scalar branch,
// scalar row base).  No LDS, no syncthreads.
#define AGG_ACC2(ent, xw)                                            \
    {                                                                \
        int r_ = (ent) & 7;                                          \
        float flo_ = __uint_as_float((xw) << 16);                    \
        float fhi_ = __uint_as_float((xw) & 0xffff0000u);            \
        if (r_ == 0)      { a0 += flo_; a1 += fhi_; }                \
        else if (r_ == 1) { b0 += flo_; b1 += fhi_; }                \
        else if (r_ == 2) { c0 += flo_; c1 += fhi_; }                \
        else if (r_ == 3) { d0 += flo_; d1 += fhi_; }                \
        else              { e0 += flo_; e1 += fhi_; }                \
    }

static __device__ __forceinline__ unsigned int agg_row_load(
        const unsigned int* __restrict__ Xcat32, int ent, int lane) {
    unsigned int row = (unsigned int)(ent >> 3);
    if (row >= (unsigned)N_NODES) row = 0u;   // crash-guard for unwritten slots
    return Xcat32[(size_t)row * 384 + lane];
}

__global__ __launch_bounds__(256) void aggregate(const int* __restrict__ offsets,
                                                 const int* __restrict__ entries,
                                                 unsigned int* __restrict__ Xcat32) {
    int tid = threadIdx.x;
    int wid = tid >> 6, lane = tid & 63;
    int n = __builtin_amdgcn_readfirstlane(blockIdx.x * 4 + wid);  // 12500 blocks
    int beg = __builtin_amdgcn_readfirstlane(offsets[n]);
    int end = __builtin_amdgcn_readfirstlane(offsets[n + 1]);
    float a0 = 0, a1 = 0, b0 = 0, b1 = 0, c0 = 0, c1 = 0, d0 = 0, d1 = 0, e0 = 0, e1 = 0;

    for (int base = beg; base < end; base += 64) {
        int cnt = end - base;
        if (cnt > 64) cnt = 64;
        // over-read past segment end is safe: entries is followed by idx32 in ws
        int eload = entries[base + lane];
        int j = 0;
        for (; j + 3 < cnt; j += 4) {       // 4 independent gathers in flight
            int en0 = __builtin_amdgcn_readlane(eload, j);
            int en1 = __builtin_amdgcn_readlane(eload, j + 1);
            int en2 = __builtin_amdgcn_readlane(eload, j + 2);
            int en3 = __builtin_amdgcn_readlane(eload, j + 3);
            unsigned int x0 = agg_row_load(Xcat32, en0, lane);
            unsigned int x1 = agg_row_load(Xcat32, en1, lane);
            unsigned int x2 = agg_row_load(Xcat32, en2, lane);
            unsigned int x3 = agg_row_load(Xcat32, en3, lane);
            AGG_ACC2(en0, x0);
            AGG_ACC2(en1, x1);
            AGG_ACC2(en2, x2);
            AGG_ACC2(en3, x3);
        }
        for (; j < cnt; ++j) {
            int en = __builtin_amdgcn_readlane(eload, j);
            unsigned int xw = agg_row_load(Xcat32, en, lane);
            AGG_ACC2(en, xw);
        }
    }

    size_t o = (size_t)n * 384 + 64 + lane;  // lane c packs cols (2c, 2c+1)
    Xcat32[o]       = (unsigned int)f2bf(a0) | ((unsigned int)f2bf(a1) << 16);
    Xcat32[o + 64]  = (unsigned int)f2bf(b0) | ((unsigned int)f2bf(b1) << 16);
    Xcat32[o + 128] = (unsigned int)f2bf(c0) | ((unsigned int)f2bf(c1) << 16);
    Xcat32[o + 192] = (unsigned int)f2bf(d0) | ((unsigned int)f2bf(d1) << 16);
    Xcat32[o + 256] = (unsigned int)f2bf(e0) | ((unsigned int)f2bf(e1) << 16);
}

// out = Xcat[50000][768] @ wcatB[128][768]^T.  128x128 tile (391 blocks),
// register prefetch of the next K-chunk issued before the MFMA section.
// This exact kernel was part of the 229.9us R2 bench.
__global__ __launch_bounds__(256) void gemm_mfma(const unsigned short* __restrict__ Xcat,
                                                 const unsigned short* __restrict__ wcatB,
                                                 float* __restrict__ outF) {
    __shared__ unsigned short xs[128 * 72];
    __shared__ unsigned short wsd[128 * 72];
    int tid = threadIdx.x;
    int m0 = blockIdx.x * 128;            // 391 blocks
    int wid = tid >> 6, lane = tid & 63;
    int wm = (wid & 1) * 64, wn = (wid >> 1) * 64;
    int lm = lane & 15, kg = lane >> 4;
    int srow = tid >> 3, scol = (tid & 7) * 8;   // staging: 32 rows/step, 4 steps

    float4v accf[4][4];
#pragma unroll
    for (int i = 0; i < 4; ++i)
#pragma unroll
        for (int j = 0; j < 4; ++j) accf[i][j] = (float4v){0.f, 0.f, 0.f, 0.f};

    short8 xr[4], wr[4];
    const short8 z8 = {0, 0, 0, 0, 0, 0, 0, 0};
#pragma unroll
    for (int i = 0; i < 4; ++i) {         // prefetch chunk 0
        int row = srow + i * 32;
        int gm = m0 + row;
        xr[i] = (gm < N_NODES) ? *(const short8*)(Xcat + (size_t)gm * KTOT + scol) : z8;
        wr[i] = *(const short8*)(wcatB + (size_t)row * KTOT + scol);
    }

    for (int kc = 0; kc < 12; ++kc) {
        if (kc) __syncthreads();          // prior compute done reading LDS
#pragma unroll
        for (int i = 0; i < 4; ++i) {
            int row = srow + i * 32;
            *(short8*)(&xs[row * 72 + scol]) = xr[i];
            *(short8*)(&wsd[row * 72 + scol]) = wr[i];
        }
        __syncthreads();
        if (kc + 1 < 12) {                // issue next-chunk loads; consumed next iter
            int kb = (kc + 1) * 64 + scol;
#pragma unroll
            for (int i = 0; i < 4; ++i) {
                int row = srow + i * 32;
                int gm = m0 + row;
                xr[i] = (gm < N_NODES) ? *(const short8*)(Xcat + (size_t)gm * KTOT + kb) : z8;
                wr[i] = *(const short8*)(wcatB + (size_t)row * KTOT + kb);
            }
        }
#pragma unroll
        for (int kb = 0; kb < 2; ++kb) {
            int k = kb * 32 + kg * 8;
            short8 a[4], b[4];
#pragma unroll
            for (int i = 0; i < 4; ++i)
                a[i] = *(const short8*)(&xs[(wm + i * 16 + lm) * 72 + k]);
#pragma unroll
            for (int j = 0; j < 4; ++j)
                b[j] = *(const short8*)(&wsd[(wn + j * 16 + lm) * 72 + k]);
#pragma unroll
            for (int i = 0; i < 4; ++i)
#pragma unroll
                for (int j = 0; j < 4; ++j)
                    accf[i][j] = __builtin_amdgcn_mfma_f32_16x16x32_bf16(a[i], b[j], accf[i][j], 0, 0, 0);
        }
    }

    // C/D: col = lane&15, row = (lane>>4)*4 + reg
#pragma unroll
    for (int i = 0; i < 4; ++i) {
        int gmb = m0 + wm + i * 16 + kg * 4;
#pragma unroll
        for (int j = 0; j < 4; ++j) {
            int gn = wn + j * 16 + lm;
#pragma unroll
            for (int r = 0; r < 4; ++r) {
                int gm = gmb + r;
                if (gm < N_NODES) outF[(size_t)gm * D + gn] = accf[i][j][r];
            }
        }
    }
}

// ---- Tier-3 fallback (tiny ws) ----
static __device__ __forceinline__ float2 readx2(const void* x, int node, int lane,
                                                int f32, int f16) {
    if (f32) return *((const float2*)x + (size_t)node * 64 + lane);
    unsigned int w = *((const unsigned int*)x + (size_t)node * 64 + lane);
    float2 r;
    if (f16) { r.x = h2f(w & 0xffffu); r.y = h2f(w >> 16); }
    else     { r.x = bf2f(w & 0xffffu); r.y = bf2f(w >> 16); }
    return r;
}

__global__ __launch_bounds__(256) void self_raw(const void* __restrict__ x,
                                                const float* __restrict__ wcatT6F,
                                                float* __restrict__ outF,
                                                const int* __restrict__ flags) {
    int t = blockIdx.x * 256 + threadIdx.x;
    int n = t >> 6, lane = t & 63;
    int f32 = flags[2], f16 = flags[6];
    float2 xp = readx2(x, n, lane, f32, f16);
    float m0 = 0.f, m1 = 0.f;
#pragma unroll 8
    for (int dp = 0; dp < 64; ++dp) {
        float xa = __shfl(xp.x, dp);
        float xc = __shfl(xp.y, dp);
        float2 w0 = *(const float2*)(wcatT6F + (size_t)(2 * dp) * D + 2 * lane);
        float2 w1 = *(const float2*)(wcatT6F + (size_t)(2 * dp + 1) * D + 2 * lane);
        m0 += xa * w0.x + xc * w1.x;
        m1 += xa * w0.y + xc * w1.y;
    }
    *((float2*)outF + (size_t)n * 64 + lane) = make_float2(m0, m1);
}

__global__ __launch_bounds__(256) void edge_raw(const int* __restrict__ src,
                                                const int* __restrict__ tgt,
                                                const int* __restrict__ et,
                                                const void* __restrict__ x,
                                                const float* __restrict__ wcatT6F,
                                                float* __restrict__ outF,
                                                const int* __restrict__ flags) {
    int t = blockIdx.x * 256 + threadIdx.x;
    int e = t >> 6, lane = t & 63;
    if (e >= N_EDGES) return;
    int f32 = flags[2], f16 = flags[6];
    int s = src[e], g = tgt[e], r = et[e];
    if ((unsigned)s >= (unsigned)N_NODES || (unsigned)g >= (unsigned)N_NODES || (unsigned)r >= 5u) return;
    float2 xp = readx2(x, s, lane, f32, f16);
    const float* wt = wcatT6F + (size_t)(1 + r) * D * D;
    float m0 = 0.f, m1 = 0.f;
#pragma unroll 8
    for (int dp = 0; dp < 64; ++dp) {
        float xa = __shfl(xp.x, dp);
        float xc = __shfl(xp.y, dp);
        float2 w0 = *(const float2*)(wt + (size_t)(2 * dp) * D + 2 * lane);
        float2 w1 = *(const float2*)(wt + (size_t)(2 * dp + 1) * D + 2 * lane);
        m0 += xa * w0.x + xc * w1.x;
        m1 += xa * w0.y + xc * w1.y;
    }
    float* ap = outF + (size_t)g * D + lane * 2;
    atomicAdd(ap + 0, m0);
    atomicAdd(ap + 1, m1);
}

extern "C" void kernel_launch(void* const* d_in, const int* in_sizes, int n_in,
                              void* d_out, int out_size, void* d_ws, size_t ws_size,
                              hipStream_t stream) {
    // identify inputs by element count (order-proof; all counts distinct)
    const void* x  = nullptr; const int* ei = nullptr; const int* et = nullptr;
    const void* B  = nullptr; const void* A = nullptr; const void* W0 = nullptr;
    for (int i = 0; i < n_in; ++i) {
        switch (in_sizes[i]) {
            case 6400000: x  = d_in[i]; break;
            case 1200000: ei = (const int*)d_in[i]; break;
            case 600000:  et = (const int*)d_in[i]; break;
            case 65536:   B  = d_in[i]; break;
            case 20:      A  = d_in[i]; break;
            case 16384:   W0 = d_in[i]; break;
            default: break;
        }
    }
    if (!x || !ei || !et || !B || !A || !W0) {
        x  = d_in[0]; ei = (const int*)d_in[1]; et = (const int*)d_in[2];
        B  = d_in[3]; A  = d_in[4]; W0 = d_in[5];
    }
    float* outF = (float*)d_out;  // [50000,128] fp32

    char* ws = (char*)d_ws;
    int*   flags   = (int*)(ws + 0);                           // 256 B
    float* wcatT6F = (float*)(ws + 256);                       // 393,216
    unsigned short* wcatB = (unsigned short*)(ws + 393472);    // 196,608
    int* offsets  = (int*)(ws + 590080);                       // 200,004
    int* cursor   = (int*)(ws + 790144);                       // 200,000
    int* cnt      = (int*)(ws + 990144);                       // 200,000
    unsigned int* scanst = (unsigned int*)(ws + 1190144);      // 1,024 (status+ticket+done)
    int* entries  = (int*)(ws + 1191168);                      // 2,400,000
    int* idx32    = (int*)(ws + 3591168);                      // 4,800,000 (own storage)
    int* et32     = (int*)(ws + 8391168);                      // 2,400,000 (own storage)
    unsigned short* Xcat = (unsigned short*)(ws + 10791168);   // 76,800,000
    const size_t needMain = 10791168ull + 76800000ull;         // 87,591,168
    const size_t needT3   = 393472ull;

    int* src32 = idx32;
    int* tgt32 = idx32 + N_EDGES;

    setup<<<NB_SCAN, 256, 0, stream>>>(flags, cnt, scanst);
    detect_all<<<355, 256, 0, stream>>>(ei, et, (const unsigned int*)x,
                                        (const unsigned int*)B, (const unsigned int*)A,
                                        (const unsigned int*)W0, flags);

    if (ws_size >= needMain) {
        norm_hist_conv<<<13666, 256, 0, stream>>>(ei, et, idx32, et32, cnt,
                                                  A, B, W0, wcatB, x, Xcat, flags);
        scan_place<<<NB_SCAN, 256, 0, stream>>>(cnt, offsets, cursor, scanst,
                                                src32, tgt32, et32, entries);
        aggregate<<<12500, 256, 0, stream>>>(offsets, entries, (unsigned int*)Xcat);
        gemm_mfma<<<391, 256, 0, stream>>>(Xcat, wcatB, outF);
    } else if (ws_size >= needT3) {
        prep_wt6_direct<<<384, 256, 0, stream>>>(A, B, W0, wcatT6F, flags);
        self_raw<<<12500, 256, 0, stream>>>(x, wcatT6F, outF, flags);
        edge_raw<<<150000, 256, 0, stream>>>(ei, ei + N_EDGES, et, x, wcatT6F, outF, flags);
    }
}

// Round 7
// 226.637 us; speedup vs baseline: 1.1712x; 1.0110x over previous
//
#include <hip/hip_runtime.h>

#define N_NODES 50000
#define N_EDGES 600000
#define D 128
#define KTOT 768          // 128 self + 5*128 relation-aggregated
#define NB_SCAN 196       // ceil(50000/256)

typedef __attribute__((ext_vector_type(8))) short short8;
typedef __attribute__((ext_vector_type(4))) float float4v;

static __device__ __forceinline__ float bf2f(unsigned int u16) {
    union { unsigned int i; float f; } v; v.i = u16 << 16; return v.f;
}
static __device__ __forceinline__ unsigned short f2bf(float f) {
    union { float f; unsigned int i; } v; v.f = f;
    unsigned int u = v.i;
    return (unsigned short)((u + 0x7FFFu + ((u >> 16) & 1u)) >> 16);  // RNE
}
static __device__ __forceinline__ float h2f(unsigned int h) {
    unsigned int s = (h >> 15) & 1u, e = (h >> 10) & 0x1fu, m = h & 0x3ffu;
    unsigned int bits = (e == 0) ? (s << 31)
                                 : ((s << 31) | ((e + 112u) << 23) | (m << 13));
    union { unsigned int i; float f; } v; v.i = bits; return v.f;
}

// flags: [0]=ei int32? [1]=et int32? [2]=x fp32? [3]=B fp32? [4]=A fp32?
//        [5]=W0 fp32?  [6]=x fp16 (if not fp32)
__global__ __launch_bounds__(256) void setup(int* __restrict__ flags,
                                             int* __restrict__ cnt,
                                             unsigned int* __restrict__ scanst) {
    int i = blockIdx.x * 256 + threadIdx.x;
    if (i < N_NODES) cnt[i] = 0;
    if (i < 8) flags[i] = 0;
    if (i < 200) scanst[i] = 0;   // status[196] + ticket
}

// ALL dtype probes in one launch; block-range partition; per-block LDS vote.
__global__ __launch_bounds__(256) void detect_all(const int* __restrict__ ei,
                                                  const int* __restrict__ et,
                                                  const unsigned int* __restrict__ x,
                                                  const unsigned int* __restrict__ B,
                                                  const unsigned int* __restrict__ A,
                                                  const unsigned int* __restrict__ W0,
                                                  int* __restrict__ flags) {
    __shared__ int sflag;
    if (threadIdx.x == 0) sflag = 0;
    __syncthreads();
    int b = blockIdx.x, acc = 0, fidx;
    if (b < 192) {                // ei: int64 high words all zero <=> flag stays 0
        fidx = 0;
        for (int i = b * 256 + threadIdx.x; i < N_EDGES; i += 192 * 256)
            acc |= ei[2 * i + 1];
    } else if (b < 240) {         // et
        fidx = 1;
        for (int i = (b - 192) * 256 + threadIdx.x; i < N_EDGES / 2; i += 48 * 256)
            acc |= et[2 * i + 1];
    } else if (b < 288) {         // x fp32? (bf16-exponent band escape on low half)
        fidx = 2;
        for (int i = (b - 240) * 256 + threadIdx.x; i < 600000; i += 48 * 256) {
            unsigned int e = (x[i] >> 7) & 0xffu;
            acc |= (e > 0xA0u || e < 0x50u) ? 1 : 0;
        }
    } else if (b < 300) {         // B fp32?
        fidx = 3;
        for (int i = (b - 288) * 256 + threadIdx.x; i < 32768; i += 12 * 256) {
            unsigned int e = (B[i] >> 7) & 0xffu;
            acc |= (e > 0xA0u || e < 0x50u) ? 1 : 0;
        }
    } else if (b == 300) {        // A fp32?
        fidx = 4;
        for (int i = threadIdx.x; i < 10; i += 256) {
            unsigned int e = (A[i] >> 7) & 0xffu;
            acc |= (e > 0xA0u || e < 0x50u) ? 1 : 0;
        }
    } else if (b < 307) {         // W0 fp32?
        fidx = 5;
        for (int i = (b - 301) * 256 + threadIdx.x; i < 8192; i += 6 * 256) {
            unsigned int e = (W0[i] >> 7) & 0xffu;
            acc |= (e > 0xA0u || e < 0x50u) ? 1 : 0;
        }
    } else {                      // x fp16? (b in 307..354)
        fidx = 6;
        for (int i = (b - 307) * 256 + threadIdx.x; i < 300000; i += 48 * 256) {
            unsigned int el = (x[i] >> 7) & 0xffu, eh = (x[i] >> 23) & 0xffu;
            acc |= (el < 0x58u || eh < 0x58u) ? 1 : 0;
        }
    }
    if (acc) sflag = 1;           // benign race
    __syncthreads();
    if (threadIdx.x == 0 && sflag) atomicOr(flags + fidx, 1);
}

static __device__ __forceinline__ float loadw(const void* p, int idx, int f32) {
    return f32 ? ((const float*)p)[idx] : bf2f(((const unsigned short*)p)[idx]);
}

// Fused: ei+et normalization + target histogram + weight build + x->bf16 conv.
// idx32/et32 are DE-ALIASED from Xcat, so conv can run in the same launch.
// blocks 0..4687: ei; 4688..7031: et; 7032..7415: wcatB; 7416..13665: conv_x.
__global__ __launch_bounds__(256) void norm_hist_conv(const int* __restrict__ ei,
                                                      const int* __restrict__ et,
                                                      int* __restrict__ idx32,
                                                      int* __restrict__ et32,
                                                      int* __restrict__ cnt,
                                                      const void* __restrict__ A,
                                                      const void* __restrict__ B,
                                                      const void* __restrict__ W0,
                                                      unsigned short* __restrict__ wcatB,
                                                      const void* __restrict__ xraw,
                                                      unsigned short* __restrict__ Xcat,
                                                      const int* __restrict__ flags) {
    int b = blockIdx.x;
    if (b < 4688) {
        int i = b * 256 + threadIdx.x;
        if (i < 2 * N_EDGES) {
            int v = flags[0] ? ei[i] : ei[2 * i];
            idx32[i] = v;
            if (i >= N_EDGES && (unsigned)v < (unsigned)N_NODES)
                atomicAdd(&cnt[v], 1);   // count by target
        }
    } else if (b < 7032) {
        int i = (b - 4688) * 256 + threadIdx.x;
        if (i < N_EDGES) et32[i] = flags[1] ? et[i] : et[2 * i];
    } else if (b < 7416) {
        int idx = (b - 7032) * 256 + threadIdx.x;  // 98304 exact
        int fB = flags[3], fA = flags[4], fW = flags[5];
        int o = idx / KTOT, k = idx % KTOT;
        float v;
        if (k < D) {
            v = loadw(W0, o * D + k, fW);
        } else {
            int r = (k - D) >> 7, d = (k - D) & 127;
            v = 0.f;
#pragma unroll
            for (int j = 0; j < 4; ++j)
                v += loadw(A, r * 4 + j, fA) * loadw(B, (j * D + o) * D + d, fB);
        }
        wcatB[idx] = f2bf(v);
    } else {
        int idx = (b - 7416) * 256 + threadIdx.x;  // 1,600,000 exact (6250 blocks)
        int n = idx >> 5, cg = idx & 31;
        int f32 = flags[2], f16 = flags[6];
        unsigned short o0, o1, o2, o3;
        if (f32) {
            float4 v = *((const float4*)xraw + idx);
            o0 = f2bf(v.x); o1 = f2bf(v.y); o2 = f2bf(v.z); o3 = f2bf(v.w);
        } else {
            uint2 v = *((const uint2*)xraw + idx);
            if (f16) {
                o0 = f2bf(h2f(v.x & 0xffffu)); o1 = f2bf(h2f(v.x >> 16));
                o2 = f2bf(h2f(v.y & 0xffffu)); o3 = f2bf(h2f(v.y >> 16));
            } else {
                o0 = v.x & 0xffffu; o1 = v.x >> 16; o2 = v.y & 0xffffu; o3 = v.y >> 16;
            }
        }
        unsigned long long pack = (unsigned long long)o0 | ((unsigned long long)o1 << 16) |
                                  ((unsigned long long)o2 << 32) | ((unsigned long long)o3 << 48);
        *(unsigned long long*)(Xcat + (size_t)n * KTOT + cg * 4) = pack;
    }
}

// Tier-3 weights: wcatT6F[slot][d][o] fp32 = W_slot[o][d]
__global__ __launch_bounds__(256) void prep_wt6_direct(const void* __restrict__ A,
                                                       const void* __restrict__ B,
                                                       const void* __restrict__ W0,
                                                       float* __restrict__ wcatT6F,
                                                       const int* __restrict__ flags) {
    int idx = blockIdx.x * 256 + threadIdx.x;  // 98304 exact
    int fB = flags[3], fA = flags[4], fW = flags[5];
    int slot = idx >> 14, d = (idx >> 7) & 127, o = idx & 127;
    float v;
    if (slot == 0) {
        v = loadw(W0, o * D + d, fW);
    } else {
        int r = slot - 1;
        v = 0.f;
#pragma unroll
        for (int j = 0; j < 4; ++j)
            v += loadw(A, r * 4 + j, fA) * loadw(B, (j * D + o) * D + d, fB);
    }
    wcatT6F[idx] = v;
}

// Single-pass scan with decoupled lookback (benched in R2; no place fusion —
// R6 proved fusing place here starves it of TLP: 196 blocks for 600k edges).
#define SC_AGG (1u << 30)
#define SC_PRE (1u << 31)
__global__ __launch_bounds__(256) void scan_fused(const int* __restrict__ cnt,
                                                  int* __restrict__ offsets,
                                                  int* __restrict__ cursor,
                                                  unsigned int* __restrict__ scanst) {
    __shared__ int sh[256];
    __shared__ int sbid, sprefix;
    unsigned int* status = scanst;        // [196]
    unsigned int* ticket = scanst + 196;
    int t = threadIdx.x;
    if (t == 0) sbid = (int)atomicAdd(ticket, 1u);
    __syncthreads();
    int bid = sbid;
    int idx = bid * 256 + t;
    int v = (idx < N_NODES) ? cnt[idx] : 0;
    sh[t] = v;
    __syncthreads();
    for (int off = 1; off < 256; off <<= 1) {
        int a = (t >= off) ? sh[t - off] : 0;
        __syncthreads();
        sh[t] += a;
        __syncthreads();
    }
    if (t == 0) {
        int total = sh[255];
        atomicExch(&status[bid], (unsigned int)total | SC_AGG);
        int prefix = 0;
        for (int j = bid - 1; j >= 0; --j) {
            unsigned int s;
            do { s = atomicAdd(&status[j], 0u); } while ((s & (SC_AGG | SC_PRE)) == 0u);
            prefix += (int)(s & 0x3FFFFFFFu);
            if (s & SC_PRE) break;
        }
        atomicExch(&status[bid], (unsigned int)(prefix + total) | SC_PRE);
        sprefix = prefix;
    }
    __syncthreads();
    int excl = sh[t] - v + sprefix;
    if (idx < N_NODES) {
        offsets[idx] = excl;
        cursor[idx] = excl;
        if (idx == N_NODES - 1) offsets[N_NODES] = excl + v;
    }
}

// place: one thread per edge (2344 blocks) — full TLP hides the scattered
// atomic+store latency (R6 lesson: 196-block fused version was 47.6us).
__global__ __launch_bounds__(256) void place(const int* __restrict__ src,
                                             const int* __restrict__ tgt,
                                             const int* __restrict__ et,
                                             int* __restrict__ cursor,
                                             int* __restrict__ entries) {
    int e = blockIdx.x * 256 + threadIdx.x;
    if (e >= N_EDGES) return;
    int s = src[e], g = tgt[e], r = et[e];
    if ((unsigned)s >= (unsigned)N_NODES || (unsigned)g >= (unsigned)N_NODES || (unsigned)r >= 5u) return;
    int pos = atomicAdd(&cursor[g], 1);
    entries[pos] = s * 8 + r;
}

// aggregate v5 (benched R1/R2): ONE wave per node; entries fetched once
// coalesced, each entry extracted via v_readlane -> SGPR (scalar branch,
// scalar row base).  No LDS, no syncthreads.
#define AGG_ACC2(ent, xw)                                            \
    {                                                                \
        int r_ = (ent) & 7;                                          \
        float flo_ = __uint_as_float((xw) << 16);                    \
        float fhi_ = __uint_as_float((xw) & 0xffff0000u);            \
        if (r_ == 0)      { a0 += flo_; a1 += fhi_; }                \
        else if (r_ == 1) { b0 += flo_; b1 += fhi_; }                \
        else if (r_ == 2) { c0 += flo_; c1 += fhi_; }                \
        else if (r_ == 3) { d0 += flo_; d1 += fhi_; }                \
        else              { e0 += flo_; e1 += fhi_; }                \
    }

static __device__ __forceinline__ unsigned int agg_row_load(
        const unsigned int* __restrict__ Xcat32, int ent, int lane) {
    unsigned int row = (unsigned int)(ent >> 3);
    if (row >= (unsigned)N_NODES) row = 0u;   // crash-guard for unwritten slots
    return Xcat32[(size_t)row * 384 + lane];
}

__global__ __launch_bounds__(256) void aggregate(const int* __restrict__ offsets,
                                                 const int* __restrict__ entries,
                                                 unsigned int* __restrict__ Xcat32) {
    int tid = threadIdx.x;
    int wid = tid >> 6, lane = tid & 63;
    int n = __builtin_amdgcn_readfirstlane(blockIdx.x * 4 + wid);  // 12500 blocks
    int beg = __builtin_amdgcn_readfirstlane(offsets[n]);
    int end = __builtin_amdgcn_readfirstlane(offsets[n + 1]);
    float a0 = 0, a1 = 0, b0 = 0, b1 = 0, c0 = 0, c1 = 0, d0 = 0, d1 = 0, e0 = 0, e1 = 0;

    for (int base = beg; base < end; base += 64) {
        int cnt = end - base;
        if (cnt > 64) cnt = 64;
        // over-read past segment end is safe: entries is followed by idx32 in ws
        int eload = entries[base + lane];
        int j = 0;
        for (; j + 3 < cnt; j += 4) {       // 4 independent gathers in flight
            int en0 = __builtin_amdgcn_readlane(eload, j);
            int en1 = __builtin_amdgcn_readlane(eload, j + 1);
            int en2 = __builtin_amdgcn_readlane(eload, j + 2);
            int en3 = __builtin_amdgcn_readlane(eload, j + 3);
            unsigned int x0 = agg_row_load(Xcat32, en0, lane);
            unsigned int x1 = agg_row_load(Xcat32, en1, lane);
            unsigned int x2 = agg_row_load(Xcat32, en2, lane);
            unsigned int x3 = agg_row_load(Xcat32, en3, lane);
            AGG_ACC2(en0, x0);
            AGG_ACC2(en1, x1);
            AGG_ACC2(en2, x2);
            AGG_ACC2(en3, x3);
        }
        for (; j < cnt; ++j) {
            int en = __builtin_amdgcn_readlane(eload, j);
            unsigned int xw = agg_row_load(Xcat32, en, lane);
            AGG_ACC2(en, xw);
        }
    }

    size_t o = (size_t)n * 384 + 64 + lane;  // lane c packs cols (2c, 2c+1)
    Xcat32[o]       = (unsigned int)f2bf(a0) | ((unsigned int)f2bf(a1) << 16);
    Xcat32[o + 64]  = (unsigned int)f2bf(b0) | ((unsigned int)f2bf(b1) << 16);
    Xcat32[o + 128] = (unsigned int)f2bf(c0) | ((unsigned int)f2bf(c1) << 16);
    Xcat32[o + 192] = (unsigned int)f2bf(d0) | ((unsigned int)f2bf(d1) << 16);
    Xcat32[o + 256] = (unsigned int)f2bf(e0) | ((unsigned int)f2bf(e1) << 16);
}

// out = Xcat[50000][768] @ wcatB[128][768]^T.  128x128 tile (391 blocks),
// register prefetch of the next K-chunk issued before the MFMA section.
// Part of both 229us benches (R2/R6).
__global__ __launch_bounds__(256) void gemm_mfma(const unsigned short* __restrict__ Xcat,
                                                 const unsigned short* __restrict__ wcatB,
                                                 float* __restrict__ outF) {
    __shared__ unsigned short xs[128 * 72];
    __shared__ unsigned short wsd[128 * 72];
    int tid = threadIdx.x;
    int m0 = blockIdx.x * 128;            // 391 blocks
    int wid = tid >> 6, lane = tid & 63;
    int wm = (wid & 1) * 64, wn = (wid >> 1) * 64;
    int lm = lane & 15, kg = lane >> 4;
    int srow = tid >> 3, scol = (tid & 7) * 8;   // staging: 32 rows/step, 4 steps

    float4v accf[4][4];
#pragma unroll
    for (int i = 0; i < 4; ++i)
#pragma unroll
        for (int j = 0; j < 4; ++j) accf[i][j] = (float4v){0.f, 0.f, 0.f, 0.f};

    short8 xr[4], wr[4];
    const short8 z8 = {0, 0, 0, 0, 0, 0, 0, 0};
#pragma unroll
    for (int i = 0; i < 4; ++i) {         // prefetch chunk 0
        int row = srow + i * 32;
        int gm = m0 + row;
        xr[i] = (gm < N_NODES) ? *(const short8*)(Xcat + (size_t)gm * KTOT + scol) : z8;
        wr[i] = *(const short8*)(wcatB + (size_t)row * KTOT + scol);
    }

    for (int kc = 0; kc < 12; ++kc) {
        if (kc) __syncthreads();          // prior compute done reading LDS
#pragma unroll
        for (int i = 0; i < 4; ++i) {
            int row = srow + i * 32;
            *(short8*)(&xs[row * 72 + scol]) = xr[i];
            *(short8*)(&wsd[row * 72 + scol]) = wr[i];
        }
        __syncthreads();
        if (kc + 1 < 12) {                // issue next-chunk loads; consumed next iter
            int kb = (kc + 1) * 64 + scol;
#pragma unroll
            for (int i = 0; i < 4; ++i) {
                int row = srow + i * 32;
                int gm = m0 + row;
                xr[i] = (gm < N_NODES) ? *(const short8*)(Xcat + (size_t)gm * KTOT + kb) : z8;
                wr[i] = *(const short8*)(wcatB + (size_t)row * KTOT + kb);
            }
        }
#pragma unroll
        for (int kb = 0; kb < 2; ++kb) {
            int k = kb * 32 + kg * 8;
            short8 a[4], b[4];
#pragma unroll
            for (int i = 0; i < 4; ++i)
                a[i] = *(const short8*)(&xs[(wm + i * 16 + lm) * 72 + k]);
#pragma unroll
            for (int j = 0; j < 4; ++j)
                b[j] = *(const short8*)(&wsd[(wn + j * 16 + lm) * 72 + k]);
#pragma unroll
            for (int i = 0; i < 4; ++i)
#pragma unroll
                for (int j = 0; j < 4; ++j)
                    accf[i][j] = __builtin_amdgcn_mfma_f32_16x16x32_bf16(a[i], b[j], accf[i][j], 0, 0, 0);
        }
    }

    // C/D: col = lane&15, row = (lane>>4)*4 + reg
#pragma unroll
    for (int i = 0; i < 4; ++i) {
        int gmb = m0 + wm + i * 16 + kg * 4;
#pragma unroll
        for (int j = 0; j < 4; ++j) {
            int gn = wn + j * 16 + lm;
#pragma unroll
            for (int r = 0; r < 4; ++r) {
                int gm = gmb + r;
                if (gm < N_NODES) outF[(size_t)gm * D + gn] = accf[i][j][r];
            }
        }
    }
}

// ---- Tier-3 fallback (tiny ws) ----
static __device__ __forceinline__ float2 readx2(const void* x, int node, int lane,
                                                int f32, int f16) {
    if (f32) return *((const float2*)x + (size_t)node * 64 + lane);
    unsigned int w = *((const unsigned int*)x + (size_t)node * 64 + lane);
    float2 r;
    if (f16) { r.x = h2f(w & 0xffffu); r.y = h2f(w >> 16); }
    else     { r.x = bf2f(w & 0xffffu); r.y = bf2f(w >> 16); }
    return r;
}

__global__ __launch_bounds__(256) void self_raw(const void* __restrict__ x,
                                                const float* __restrict__ wcatT6F,
                                                float* __restrict__ outF,
                                                const int* __restrict__ flags) {
    int t = blockIdx.x * 256 + threadIdx.x;
    int n = t >> 6, lane = t & 63;
    int f32 = flags[2], f16 = flags[6];
    float2 xp = readx2(x, n, lane, f32, f16);
    float m0 = 0.f, m1 = 0.f;
#pragma unroll 8
    for (int dp = 0; dp < 64; ++dp) {
        float xa = __shfl(xp.x, dp);
        float xc = __shfl(xp.y, dp);
        float2 w0 = *(const float2*)(wcatT6F + (size_t)(2 * dp) * D + 2 * lane);
        float2 w1 = *(const float2*)(wcatT6F + (size_t)(2 * dp + 1) * D + 2 * lane);
        m0 += xa * w0.x + xc * w1.x;
        m1 += xa * w0.y + xc * w1.y;
    }
    *((float2*)outF + (size_t)n * 64 + lane) = make_float2(m0, m1);
}

__global__ __launch_bounds__(256) void edge_raw(const int* __restrict__ src,
                                                const int* __restrict__ tgt,
                                                const int* __restrict__ et,
                                                const void* __restrict__ x,
                                                const float* __restrict__ wcatT6F,
                                                float* __restrict__ outF,
                                                const int* __restrict__ flags) {
    int t = blockIdx.x * 256 + threadIdx.x;
    int e = t >> 6, lane = t & 63;
    if (e >= N_EDGES) return;
    int f32 = flags[2], f16 = flags[6];
    int s = src[e], g = tgt[e], r = et[e];
    if ((unsigned)s >= (unsigned)N_NODES || (unsigned)g >= (unsigned)N_NODES || (unsigned)r >= 5u) return;
    float2 xp = readx2(x, s, lane, f32, f16);
    const float* wt = wcatT6F + (size_t)(1 + r) * D * D;
    float m0 = 0.f, m1 = 0.f;
#pragma unroll 8
    for (int dp = 0; dp < 64; ++dp) {
        float xa = __shfl(xp.x, dp);
        float xc = __shfl(xp.y, dp);
        float2 w0 = *(const float2*)(wt + (size_t)(2 * dp) * D + 2 * lane);
        float2 w1 = *(const float2*)(wt + (size_t)(2 * dp + 1) * D + 2 * lane);
        m0 += xa * w0.x + xc * w1.x;
        m1 += xa * w0.y + xc * w1.y;
    }
    float* ap = outF + (size_t)g * D + lane * 2;
    atomicAdd(ap + 0, m0);
    atomicAdd(ap + 1, m1);
}

extern "C" void kernel_launch(void* const* d_in, const int* in_sizes, int n_in,
                              void* d_out, int out_size, void* d_ws, size_t ws_size,
                              hipStream_t stream) {
    // identify inputs by element count (order-proof; all counts distinct)
    const void* x  = nullptr; const int* ei = nullptr; const int* et = nullptr;
    const void* B  = nullptr; const void* A = nullptr; const void* W0 = nullptr;
    for (int i = 0; i < n_in; ++i) {
        switch (in_sizes[i]) {
            case 6400000: x  = d_in[i]; break;
            case 1200000: ei = (const int*)d_in[i]; break;
            case 600000:  et = (const int*)d_in[i]; break;
            case 65536:   B  = d_in[i]; break;
            case 20:      A  = d_in[i]; break;
            case 16384:   W0 = d_in[i]; break;
            default: break;
        }
    }
    if (!x || !ei || !et || !B || !A || !W0) {
        x  = d_in[0]; ei = (const int*)d_in[1]; et = (const int*)d_in[2];
        B  = d_in[3]; A  = d_in[4]; W0 = d_in[5];
    }
    float* outF = (float*)d_out;  // [50000,128] fp32

    char* ws = (char*)d_ws;
    int*   flags   = (int*)(ws + 0);                           // 256 B
    float* wcatT6F = (float*)(ws + 256);                       // 393,216
    unsigned short* wcatB = (unsigned short*)(ws + 393472);    // 196,608
    int* offsets  = (int*)(ws + 590080);                       // 200,004
    int* cursor   = (int*)(ws + 790144);                       // 200,000
    int* cnt      = (int*)(ws + 990144);                       // 200,000
    unsigned int* scanst = (unsigned int*)(ws + 1190144);      // 1,024 (status+ticket)
    int* entries  = (int*)(ws + 1191168);                      // 2,400,000
    int* idx32    = (int*)(ws + 3591168);                      // 4,800,000 (own storage)
    int* et32     = (int*)(ws + 8391168);                      // 2,400,000 (own storage)
    unsigned short* Xcat = (unsigned short*)(ws + 10791168);   // 76,800,000
    const size_t needMain = 10791168ull + 76800000ull;         // 87,591,168
    const size_t needT3   = 393472ull;

    int* src32 = idx32;
    int* tgt32 = idx32 + N_EDGES;

    setup<<<NB_SCAN, 256, 0, stream>>>(flags, cnt, scanst);
    detect_all<<<355, 256, 0, stream>>>(ei, et, (const unsigned int*)x,
                                        (const unsigned int*)B, (const unsigned int*)A,
                                        (const unsigned int*)W0, flags);

    if (ws_size >= needMain) {
        norm_hist_conv<<<13666, 256, 0, stream>>>(ei, et, idx32, et32, cnt,
                                                  A, B, W0, wcatB, x, Xcat, flags);
        scan_fused<<<NB_SCAN, 256, 0, stream>>>(cnt, offsets, cursor, scanst);
        place<<<2344, 256, 0, stream>>>(src32, tgt32, et32, cursor, entries);
        aggregate<<<12500, 256, 0, stream>>>(offsets, entries, (unsigned int*)Xcat);
        gemm_mfma<<<391, 256, 0, stream>>>(Xcat, wcatB, outF);
    } else if (ws_size >= needT3) {
        prep_wt6_direct<<<384, 256, 0, stream>>>(A, B, W0, wcatT6F, flags);
        self_raw<<<12500, 256, 0, stream>>>(x, wcatT6F, outF, flags);
        edge_raw<<<150000, 256, 0, stream>>>(ei, ei + N_EDGES, et, x, wcatT6F, outF, flags);
    }
}